// Round 15
// baseline (249.787 us; speedup 1.0000x reference)
//
#include <hip/hip_runtime.h>

// MultiHeadAttn fused block, MI355X/gfx950.
// Round 15: attn occupancy fix — QBLK 128->64, 128-thread blocks (2 waves x
// 32 q-rows), grid 1024 -> 4 independent blocks/CU (LDS 40960B x4 = 160KiB
// exact). k-loop body identical to round 14 (pass, 234.7us; attn 100.0us);
// only staging loop counts, mask preload, and output indexing resized.

typedef __attribute__((ext_vector_type(4))) float f32x4;
typedef __attribute__((ext_vector_type(16))) float f32x16;
typedef __attribute__((ext_vector_type(8))) short s16x8;
typedef __attribute__((ext_vector_type(4))) short s16x4;
typedef __attribute__((ext_vector_type(4))) unsigned int u32x4;

__device__ __forceinline__ unsigned short f2bf(float f) {
  union { float f; unsigned u; } x; x.f = f;
  unsigned r = x.u + 0x7fffu + ((x.u >> 16) & 1u);
  return (unsigned short)(r >> 16);
}
__device__ __forceinline__ float bf2f(unsigned short h) {
  union { unsigned u; float f; } x; x.u = ((unsigned)h) << 16;
  return x.f;
}

__device__ __forceinline__ void gload_lds16(const void* g, void* l) {
  __builtin_amdgcn_global_load_lds(
      (const __attribute__((address_space(1))) unsigned int*)g,
      (__attribute__((address_space(3))) unsigned int*)l, 16, 0, 0);
}

__device__ __forceinline__ unsigned lds_off(const void* p) {
  return (unsigned)(size_t)(const __attribute__((address_space(3))) void*)p;
}

// Fused convert: y in {0,1,2} -> q/k/v (n4big each); y==3 -> 4 weights,
// selected by i>>18 (n4w = 1024*1024/4 = 2^18 float4 elems per weight).
__global__ __launch_bounds__(256) void cvt_fused(
    const float* __restrict__ q, const float* __restrict__ k,
    const float* __restrict__ v, const float* __restrict__ W0,
    const float* __restrict__ W1, const float* __restrict__ W2,
    const float* __restrict__ W3, unsigned short* __restrict__ qd,
    unsigned short* __restrict__ kd, unsigned short* __restrict__ vd,
    unsigned short* __restrict__ W0d, unsigned short* __restrict__ W1d,
    unsigned short* __restrict__ W2d, unsigned short* __restrict__ W3d,
    int n4big) {
  const int by = blockIdx.y;
  int i = blockIdx.x * blockDim.x + threadIdx.x;
  const float* s;
  unsigned short* d;
  if (by < 3) {
    if (i >= n4big) return;
    s = by == 0 ? q : by == 1 ? k : v;
    d = by == 0 ? qd : by == 1 ? kd : vd;
  } else {
    if (i >= 4 * 262144) return;
    const int wsel = i >> 18;
    s = wsel == 0 ? W0 : wsel == 1 ? W1 : wsel == 2 ? W2 : W3;
    d = wsel == 0 ? W0d : wsel == 1 ? W1d : wsel == 2 ? W2d : W3d;
    i &= 262143;
  }
  float4 f = reinterpret_cast<const float4*>(s)[i];
  s16x4 o;
  o[0] = (short)f2bf(f.x); o[1] = (short)f2bf(f.y);
  o[2] = (short)f2bf(f.z); o[3] = (short)f2bf(f.w);
  reinterpret_cast<s16x4*>(d)[i] = o;
}

// C[M,N] = A[M,K] @ B[N,K]^T, all bf16 (C bf16 out), optional bias+relu.
// 128x128 tile, BK=32, 4 waves (2x2), 4x4 16x16x32 frags per wave.
template<int RELU_BIAS>
__global__ __launch_bounds__(256) void gemm_bt(
    const unsigned short* __restrict__ A, const unsigned short* __restrict__ B,
    unsigned short* __restrict__ C, const float* __restrict__ bias,
    int M, int N, int K) {
  __shared__ __align__(16) unsigned short As[128 * 32];
  __shared__ __align__(16) unsigned short Bs[128 * 32];
  const int tid = threadIdx.x;
  const int lane = tid & 63;
  const int w = tid >> 6;
  const int brow = blockIdx.x * 128;
  const int bcol = blockIdx.y * 128;
  const int wr = (w >> 1) * 64;
  const int wc = (w & 1) * 64;

  f32x4 acc[4][4] = {};

  const int srow = w * 32 + (lane >> 2);  // + j*16
  const int scol = (lane & 3) * 8;
  const int rfrag = lane & 15;
  const int kfrag = (lane >> 4) * 8;

  for (int k0 = 0; k0 < K; k0 += 32) {
    __syncthreads();
#pragma unroll
    for (int j = 0; j < 2; ++j) {
      const unsigned short* ga = A + (size_t)(brow + srow + j * 16) * K + k0 + scol;
      gload_lds16(ga, As + (w * 1024 + j * 512));
      const unsigned short* gb = B + (size_t)(bcol + srow + j * 16) * K + k0 + scol;
      gload_lds16(gb, Bs + (w * 1024 + j * 512));
    }
    asm volatile("s_waitcnt vmcnt(0)" ::: "memory");
    __syncthreads();
    s16x8 a[4], b[4];
#pragma unroll
    for (int m = 0; m < 4; ++m)
      a[m] = *(const s16x8*)(As + (wr + m * 16 + rfrag) * 32 + kfrag);
#pragma unroll
    for (int n = 0; n < 4; ++n)
      b[n] = *(const s16x8*)(Bs + (wc + n * 16 + rfrag) * 32 + kfrag);
#pragma unroll
    for (int m = 0; m < 4; ++m)
#pragma unroll
      for (int n = 0; n < 4; ++n)
        acc[m][n] = __builtin_amdgcn_mfma_f32_16x16x32_bf16(a[m], b[n], acc[m][n], 0, 0, 0);
  }

  const int crow = brow + wr + ((lane >> 4) * 4);
  const int ccol = bcol + wc + (lane & 15);
  float bv[4];
  if (RELU_BIAS) {
#pragma unroll
    for (int n = 0; n < 4; ++n) bv[n] = bias[ccol + n * 16];
  }
#pragma unroll
  for (int m = 0; m < 4; ++m)
#pragma unroll
    for (int n = 0; n < 4; ++n)
#pragma unroll
      for (int r = 0; r < 4; ++r) {
        float vv = acc[m][n][r];
        if (RELU_BIAS) vv = fmaxf(vv + bv[n], 0.f);
        C[(size_t)(crow + m * 16 + r) * N + ccol + n * 16] = f2bf(vv);
      }
}

// 3 projection GEMMs in one dispatch; blockIdx.z selects (A,B,C) triple.
__global__ __launch_bounds__(256) void gemm_proj3(
    const unsigned short* __restrict__ A0, const unsigned short* __restrict__ A1,
    const unsigned short* __restrict__ A2, const unsigned short* __restrict__ B0,
    const unsigned short* __restrict__ B1, const unsigned short* __restrict__ B2,
    unsigned short* __restrict__ C0, unsigned short* __restrict__ C1,
    unsigned short* __restrict__ C2, int M, int N, int K) {
  const int z = blockIdx.z;
  const unsigned short* __restrict__ A = z == 0 ? A0 : z == 1 ? A1 : A2;
  const unsigned short* __restrict__ B = z == 0 ? B0 : z == 1 ? B1 : B2;
  unsigned short* __restrict__ C = z == 0 ? C0 : z == 1 ? C1 : C2;

  __shared__ __align__(16) unsigned short As[128 * 32];
  __shared__ __align__(16) unsigned short Bs[128 * 32];
  const int tid = threadIdx.x;
  const int lane = tid & 63;
  const int w = tid >> 6;
  const int brow = blockIdx.x * 128;
  const int bcol = blockIdx.y * 128;
  const int wr = (w >> 1) * 64;
  const int wc = (w & 1) * 64;

  f32x4 acc[4][4] = {};

  const int srow = w * 32 + (lane >> 2);
  const int scol = (lane & 3) * 8;
  const int rfrag = lane & 15;
  const int kfrag = (lane >> 4) * 8;

  for (int k0 = 0; k0 < K; k0 += 32) {
    __syncthreads();
#pragma unroll
    for (int j = 0; j < 2; ++j) {
      const unsigned short* ga = A + (size_t)(brow + srow + j * 16) * K + k0 + scol;
      gload_lds16(ga, As + (w * 1024 + j * 512));
      const unsigned short* gb = B + (size_t)(bcol + srow + j * 16) * K + k0 + scol;
      gload_lds16(gb, Bs + (w * 1024 + j * 512));
    }
    asm volatile("s_waitcnt vmcnt(0)" ::: "memory");
    __syncthreads();
    s16x8 a[4], b[4];
#pragma unroll
    for (int m = 0; m < 4; ++m)
      a[m] = *(const s16x8*)(As + (wr + m * 16 + rfrag) * 32 + kfrag);
#pragma unroll
    for (int n = 0; n < 4; ++n)
      b[n] = *(const s16x8*)(Bs + (wc + n * 16 + rfrag) * 32 + kfrag);
#pragma unroll
    for (int m = 0; m < 4; ++m)
#pragma unroll
      for (int n = 0; n < 4; ++n)
        acc[m][n] = __builtin_amdgcn_mfma_f32_16x16x32_bf16(a[m], b[n], acc[m][n], 0, 0, 0);
  }

  const int crow = brow + wr + ((lane >> 4) * 4);
  const int ccol = bcol + wc + (lane & 15);
#pragma unroll
  for (int m = 0; m < 4; ++m)
#pragma unroll
    for (int n = 0; n < 4; ++n)
#pragma unroll
      for (int r = 0; r < 4; ++r)
        C[(size_t)(crow + m * 16 + r) * N + ccol + n * 16] = f2bf(acc[m][n][r]);
}

// Flash attention on 32x32x16 MFMA. Grid 1024 (32 q-tiles x 32 bh), 128 thr
// (2 waves x 32 q-rows). XCD remap: xcd = L&7 owns bh in [4*xcd, 4*xcd+4).
// LDS (u16): Ks [0,8192) [64][128] col-XOR-swizzled rows;
//            Vs [8192,16384) subtiled [k/4][d/16][4][16].
// smaskF: f32[2048] additive mask. Total 40960B -> 4 blocks/CU.
// Q tile [64][128] staged in Ks+Vs pre-loop, hoisted to qf[8].
// Swapped QK^T: S^T = mfma32(Kfrag, Qfrag): lane owns q = lane&31 (+w*32);
// k rows = kb*32 + (reg&3) + 8*(reg>>2) + 4*(lane>>5). Softmax in-lane.
// P->PV A-frags in-register: cvt_pk + v_permlane32_swap_b32 (T12).
__global__ __launch_bounds__(128, 2) void attn_fused(
    const unsigned short* __restrict__ Qp, const unsigned short* __restrict__ Kp,
    const unsigned short* __restrict__ Vp, const int* __restrict__ mask,
    unsigned short* __restrict__ Att) {
  constexpr int DD = 1024, NK = 2048;
  __shared__ __align__(16) unsigned short lds[16384];
  __shared__ __align__(16) float smaskF[2048];
  unsigned short* Ks = lds;
  unsigned short* Vs = lds + 8192;

  const int tid = threadIdx.x, lane = tid & 63, w = tid >> 6;  // w in {0,1}
  const int quad = lane >> 4, lq = lane & 15;
  const int hi = lane >> 5, q5 = lane & 31;
  const int L = blockIdx.x;
  const int bh = (L & 7) * 4 + (L >> 8);   // 4 heads per XCD
  const int qt = (L >> 3) & 31;
  const int b = bh >> 3, h = bh & 7;
  const int q0 = qt * 64;
  const unsigned short* Qbase = Qp + ((size_t)b * 2048 + q0) * DD + h * 128;
  const unsigned short* Kbase = Kp + (size_t)b * 2048 * DD + h * 128;
  const unsigned short* Vbase = Vp + (size_t)b * 2048 * DD + h * 128;

  // ---- stage Q tile [64][128] (linear, Ks+Vs area) then hoist frags ----
#pragma unroll
  for (int j = 0; j < 8; ++j) {
    int row = w * 32 + j * 4 + quad;
    const unsigned short* g = Qbase + (size_t)row * DD + lq * 8;
    gload_lds16(g, lds + w * 4096 + j * 512);
  }
  asm volatile("s_waitcnt vmcnt(0)" ::: "memory");
  __syncthreads();
  // B-frag for mfma32: lane holds Q[q = w*32 + q5][d = ds*16 + hi*8 + j]
  s16x8 qf[8];
#pragma unroll
  for (int ds = 0; ds < 8; ++ds)
    qf[ds] = *(const s16x8*)(lds + (w * 32 + q5) * 128 + ds * 16 + hi * 8);

  // ---- preload full additive mask row -> smaskF (128 thr x 4 int4) ----
  {
    const int4* mp = (const int4*)(mask + b * NK);
#pragma unroll
    for (int i = 0; i < 4; ++i) {
      int4 m0 = mp[tid + i * 128];
      f32x4 w0;
      w0[0] = m0.x ? -1e30f : 0.f; w0[1] = m0.y ? -1e30f : 0.f;
      w0[2] = m0.z ? -1e30f : 0.f; w0[3] = m0.w ? -1e30f : 0.f;
      *(f32x4*)(smaskF + 4 * (tid + i * 128)) = w0;
    }
  }

  const unsigned vb0 = lds_off(Vs);
  const int swzq = (q5 & 7) << 4;

  f32x16 o[4] = {};
  float mrow = -1e30f, lrow = 0.f;

  for (int kt = 0; kt < NK / 64; ++kt) {
    const int k0 = kt * 64;
    __syncthreads();  // prior iteration's LDS reads done before overwrite
    // stage K [64][128] with XOR-swizzled SOURCE (linear LDS dest)
#pragma unroll
    for (int j = 0; j < 8; ++j) {
      int row = w * 32 + j * 4 + quad;
      int cb = lq * 16;                      // byte chunk within 256B row
      int cbs = cb ^ ((row & 7) << 4);       // involution on bits 4..6
      const unsigned short* g = Kbase + (size_t)(k0 + row) * DD + (cbs >> 1);
      gload_lds16(g, Ks + w * 4096 + j * 512);
    }
    // stage V into subtile layout [k/4][d/16][4][16] via pre-swizzled source
#pragma unroll
    for (int it = 0; it < 8; ++it) {
      int s = w * 512 + it * 64 + lane;
      int kk = ((s >> 6) << 2) | ((s >> 1) & 3);
      int dd = (((s >> 3) & 7) << 4) | ((s & 1) << 3);
      const unsigned short* g = Vbase + (size_t)(k0 + kk) * DD + dd;
      gload_lds16(g, Vs + (size_t)(w * 512 + it * 64) * 8);
    }
    asm volatile("s_waitcnt vmcnt(0)" ::: "memory");
    __syncthreads();

    // ---- S^T = (K Q^T)/32 + mask ----
    f32x16 acc0 = {}, acc1 = {};
    __builtin_amdgcn_s_setprio(1);
#pragma unroll
    for (int ds = 0; ds < 8; ++ds) {
      int cbs = (ds * 32 + hi * 16) ^ swzq;  // row&7 == q5&7 for both kb
      s16x8 kf0 = *(const s16x8*)((const char*)Ks + q5 * 256 + cbs);
      s16x8 kf1 = *(const s16x8*)((const char*)Ks + (q5 + 32) * 256 + cbs);
      acc0 = __builtin_amdgcn_mfma_f32_32x32x16_bf16(kf0, qf[ds], acc0, 0, 0, 0);
      acc1 = __builtin_amdgcn_mfma_f32_32x32x16_bf16(kf1, qf[ds], acc1, 0, 0, 0);
    }
    __builtin_amdgcn_s_setprio(0);

    // scale + mask; reg -> k = kb*32 + (reg&3) + 8*(reg>>2) + 4*hi
    float sv0[16], sv1[16];
#pragma unroll
    for (int g2 = 0; g2 < 4; ++g2) {
      f32x4 m0 = *(const f32x4*)(smaskF + k0 + g2 * 8 + hi * 4);
      f32x4 m1 = *(const f32x4*)(smaskF + k0 + 32 + g2 * 8 + hi * 4);
#pragma unroll
      for (int j2 = 0; j2 < 4; ++j2) {
        sv0[g2 * 4 + j2] = fmaf(acc0[g2 * 4 + j2], 0.03125f, m0[j2]);
        sv1[g2 * 4 + j2] = fmaf(acc1[g2 * 4 + j2], 0.03125f, m1[j2]);
      }
    }

    // ---- online softmax, in-lane over 32 values + one shfl ----
    float tm = fmaxf(sv0[0], sv1[0]);
#pragma unroll
    for (int r = 1; r < 16; ++r) tm = fmaxf(tm, fmaxf(sv0[r], sv1[r]));
    tm = fmaxf(tm, __shfl_xor(tm, 32, 64));
    // T13 defer-max
    const bool up = !__all(tm - mrow <= 8.f);
    float al = 1.f;
    if (up) {
      float mn = fmaxf(mrow, tm);
      al = __expf(mrow - mn);
      mrow = mn;
    }
    // ---- P = exp(S - m); build PV A-frags in-register (T12) ----
    float rs = 0.f;
    s16x8 pa[4];
    auto packP = [&](const float (&sv)[16], s16x8* paOut) {
      float p[16];
#pragma unroll
      for (int r = 0; r < 16; ++r) {
        p[r] = __expf(sv[r] - mrow);
        rs += p[r];
      }
#pragma unroll
      for (int i2 = 0; i2 < 2; ++i2) {
        unsigned a0, b0, a1, b1;
        asm("v_cvt_pk_bf16_f32 %0, %1, %2" : "=v"(a0) : "v"(p[i2 * 8 + 0]), "v"(p[i2 * 8 + 1]));
        asm("v_cvt_pk_bf16_f32 %0, %1, %2" : "=v"(b0) : "v"(p[i2 * 8 + 4]), "v"(p[i2 * 8 + 5]));
        asm("v_cvt_pk_bf16_f32 %0, %1, %2" : "=v"(a1) : "v"(p[i2 * 8 + 2]), "v"(p[i2 * 8 + 3]));
        asm("v_cvt_pk_bf16_f32 %0, %1, %2" : "=v"(b1) : "v"(p[i2 * 8 + 6]), "v"(p[i2 * 8 + 7]));
        asm volatile("v_permlane32_swap_b32 %0, %1" : "+v"(a0), "+v"(b0));
        asm volatile("v_permlane32_swap_b32 %0, %1" : "+v"(a1), "+v"(b1));
        u32x4 wv;
        wv[0] = a0; wv[1] = a1; wv[2] = b0; wv[3] = b1;
        paOut[i2] = *(s16x8*)&wv;
      }
    };
    packP(sv0, &pa[0]);
    packP(sv1, &pa[2]);
    rs += __shfl_xor(rs, 32, 64);
    lrow = lrow * al + rs;
    if (up) {
#pragma unroll
      for (int reg = 0; reg < 16; ++reg) {
        float alo = __shfl(al, (reg & 3) + 8 * (reg >> 2) + 4 * hi, 64);
#pragma unroll
        for (int db = 0; db < 4; ++db) o[db][reg] *= alo;
      }
    }

    // ---- O += P V (pa in regs; V via ds_read_b64_tr_b16) ----
#pragma unroll
    for (int db = 0; db < 4; ++db) {
      s16x4 vlo[4], vhi[4];
#pragma unroll
      for (int kb2 = 0; kb2 < 4; ++kb2) {
        const unsigned va = vb0 + (kb2 * 4 + hi * 2) * 1024 +
                            (db * 2 + (quad & 1)) * 128 + lq * 8;
        asm volatile("ds_read_b64_tr_b16 %0, %2\n\t"
                     "ds_read_b64_tr_b16 %1, %2 offset:1024"
                     : "=&v"(vlo[kb2]), "=&v"(vhi[kb2])
                     : "v"(va)
                     : "memory");
      }
      asm volatile("s_waitcnt lgkmcnt(0)" ::: "memory");
      __builtin_amdgcn_sched_barrier(0);
      __builtin_amdgcn_s_setprio(1);
#pragma unroll
      for (int kb2 = 0; kb2 < 4; ++kb2) {
        s16x8 vv;
#pragma unroll
        for (int j = 0; j < 4; ++j) { vv[j] = vlo[kb2][j]; vv[4 + j] = vhi[kb2][j]; }
        o[db] = __builtin_amdgcn_mfma_f32_32x32x16_bf16(pa[kb2], vv, o[db], 0, 0, 0);
      }
      __builtin_amdgcn_s_setprio(0);
    }
  }

  // ---- normalize + write ----
  float inv = (mrow <= -1e29f || lrow <= 0.f) ? 0.f : 1.f / lrow;
#pragma unroll
  for (int reg = 0; reg < 16; ++reg) {
    const int rown = (reg & 3) + 8 * (reg >> 2) + 4 * hi;
    float invo = __shfl(inv, rown, 64);
    const int q = q0 + w * 32 + rown;
#pragma unroll
    for (int db = 0; db < 4; ++db) {
      Att[((size_t)b * 2048 + q) * DD + h * 128 + db * 32 + q5] =
          f2bf(o[db][reg] * invo);
    }
  }
}

// out = LayerNorm(X + Y) * g + b. One block per 1024-elem row.
template<int OUT_F32>
__global__ __launch_bounds__(256) void add_ln(
    const unsigned short* __restrict__ X, const unsigned short* __restrict__ Y,
    const float* __restrict__ gam, const float* __restrict__ bet,
    void* __restrict__ out) {
  const int row = blockIdx.x;
  const int tid = threadIdx.x;
  const int lane = tid & 63, w = tid >> 6;
  __shared__ float rbuf[8];
  const size_t base = (size_t)row * 1024 + tid * 4;
  s16x4 xa = *(const s16x4*)(X + base);
  s16x4 yb = *(const s16x4*)(Y + base);
  float x[4];
  float s1 = 0.f, s2 = 0.f;
#pragma unroll
  for (int j = 0; j < 4; ++j) {
    x[j] = bf2f((unsigned short)xa[j]) + bf2f((unsigned short)yb[j]);
    s1 += x[j];
    s2 += x[j] * x[j];
  }
#pragma unroll
  for (int d = 1; d < 64; d <<= 1) {
    s1 += __shfl_xor(s1, d, 64);
    s2 += __shfl_xor(s2, d, 64);
  }
  if (lane == 0) { rbuf[w] = s1; rbuf[4 + w] = s2; }
  __syncthreads();
  float t1 = rbuf[0] + rbuf[1] + rbuf[2] + rbuf[3];
  float t2 = rbuf[4] + rbuf[5] + rbuf[6] + rbuf[7];
  float mu = t1 * (1.f / 1024.f);
  float var = t2 * (1.f / 1024.f) - mu * mu;
  float rstd = rsqrtf(fmaxf(var, 0.f) + 1e-5f);
  float4 g4 = *(const float4*)(gam + tid * 4);
  float4 b4 = *(const float4*)(bet + tid * 4);
  float gg[4] = {g4.x, g4.y, g4.z, g4.w};
  float bb[4] = {b4.x, b4.y, b4.z, b4.w};
  if (OUT_F32) {
    float4 o4;
    o4.x = (x[0] - mu) * rstd * gg[0] + bb[0];
    o4.y = (x[1] - mu) * rstd * gg[1] + bb[1];
    o4.z = (x[2] - mu) * rstd * gg[2] + bb[2];
    o4.w = (x[3] - mu) * rstd * gg[3] + bb[3];
    *(float4*)((float*)out + base) = o4;
  } else {
    s16x4 o;
#pragma unroll
    for (int j = 0; j < 4; ++j)
      o[j] = (short)f2bf((x[j] - mu) * rstd * gg[j] + bb[j]);
    *(s16x4*)((unsigned short*)out + base) = o;
  }
}

extern "C" void kernel_launch(void* const* d_in, const int* in_sizes, int n_in,
                              void* d_out, int out_size, void* d_ws, size_t ws_size,
                              hipStream_t stream) {
  const float* q  = (const float*)d_in[0];
  const float* k  = (const float*)d_in[1];
  const float* v  = (const float*)d_in[2];
  const int* msk  = (const int*)d_in[3];
  const float* Wq = (const float*)d_in[4];
  const float* Wk = (const float*)d_in[5];
  const float* Wv = (const float*)d_in[6];
  const float* Wo = (const float*)d_in[7];
  const float* bo = (const float*)d_in[8];
  const float* g1 = (const float*)d_in[9];
  const float* b1 = (const float*)d_in[10];
  const float* g2 = (const float*)d_in[11];
  const float* b2 = (const float*)d_in[12];
  float* out = (float*)d_out;

  char* ws = (char*)d_ws;
  const size_t S = (size_t)8192 * 1024 * 2;
  unsigned short* qb  = (unsigned short*)(ws + 0 * S);
  unsigned short* kb  = (unsigned short*)(ws + 1 * S);
  unsigned short* vb  = (unsigned short*)(ws + 2 * S);
  unsigned short* qpb = (unsigned short*)(ws + 3 * S);
  unsigned short* kpb = (unsigned short*)(ws + 4 * S);
  unsigned short* vpb = (unsigned short*)(ws + 5 * S);
  unsigned short* attb = qb;  // reuse: q bf16 dead after proj
  unsigned short* h1b  = kb;
  unsigned short* h2b  = vb;
  unsigned short* Wqb = (unsigned short*)(ws + 6 * S);
  unsigned short* Wkb = Wqb + (size_t)1024 * 1024;
  unsigned short* Wvb = Wkb + (size_t)1024 * 1024;
  unsigned short* Wob = Wvb + (size_t)1024 * 1024;

  const int n4big = 8192 * 1024 / 4;
  cvt_fused<<<dim3(8192, 4), 256, 0, stream>>>(
      q, k, v, Wq, Wk, Wv, Wo, qb, kb, vb, Wqb, Wkb, Wvb, Wob, n4big);

  gemm_proj3<<<dim3(64, 8, 3), 256, 0, stream>>>(
      qb, kb, vb, Wqb, Wkb, Wvb, qpb, kpb, vpb, 8192, 1024, 1024);

  attn_fused<<<1024, 128, 0, stream>>>(qpb, kpb, vpb, msk, attb);

  add_ln<0><<<8192, 256, 0, stream>>>(qpb, attb, g1, b1, (void*)h1b);
  gemm_bt<1><<<dim3(64, 8), 256, 0, stream>>>(h1b, Wob, h2b, bo, 8192, 1024, 1024);
  add_ln<1><<<8192, 256, 0, stream>>>(h1b, h2b, g2, b2, (void*)out);
}

// Round 16
// 235.265 us; speedup vs baseline: 1.0617x; 1.0617x over previous
//
#include <hip/hip_runtime.h>

// MultiHeadAttn fused block, MI355X/gfx950.
// Round 16: attn reverted byte-exact to round 14 (best: attn 100.0us,
// total 234.7us; round-15 QBLK split regressed to 121us -> dropped).
// New: XCD-aware block remap (T1) in both GEMM kernels — each XCD owns an
// 8x8 tile-block (A 2MB + B 2MB = its 4MB L2), A fetched ~once from HBM.

typedef __attribute__((ext_vector_type(4))) float f32x4;
typedef __attribute__((ext_vector_type(16))) float f32x16;
typedef __attribute__((ext_vector_type(8))) short s16x8;
typedef __attribute__((ext_vector_type(4))) short s16x4;
typedef __attribute__((ext_vector_type(4))) unsigned int u32x4;

__device__ __forceinline__ unsigned short f2bf(float f) {
  union { float f; unsigned u; } x; x.f = f;
  unsigned r = x.u + 0x7fffu + ((x.u >> 16) & 1u);
  return (unsigned short)(r >> 16);
}
__device__ __forceinline__ float bf2f(unsigned short h) {
  union { unsigned u; float f; } x; x.u = ((unsigned)h) << 16;
  return x.f;
}

__device__ __forceinline__ void gload_lds16(const void* g, void* l) {
  __builtin_amdgcn_global_load_lds(
      (const __attribute__((address_space(1))) unsigned int*)g,
      (__attribute__((address_space(3))) unsigned int*)l, 16, 0, 0);
}

__device__ __forceinline__ unsigned lds_off(const void* p) {
  return (unsigned)(size_t)(const __attribute__((address_space(3))) void*)p;
}

// Fused convert: y in {0,1,2} -> q/k/v (n4big each); y==3 -> 4 weights,
// selected by i>>18 (n4w = 1024*1024/4 = 2^18 float4 elems per weight).
__global__ __launch_bounds__(256) void cvt_fused(
    const float* __restrict__ q, const float* __restrict__ k,
    const float* __restrict__ v, const float* __restrict__ W0,
    const float* __restrict__ W1, const float* __restrict__ W2,
    const float* __restrict__ W3, unsigned short* __restrict__ qd,
    unsigned short* __restrict__ kd, unsigned short* __restrict__ vd,
    unsigned short* __restrict__ W0d, unsigned short* __restrict__ W1d,
    unsigned short* __restrict__ W2d, unsigned short* __restrict__ W3d,
    int n4big) {
  const int by = blockIdx.y;
  int i = blockIdx.x * blockDim.x + threadIdx.x;
  const float* s;
  unsigned short* d;
  if (by < 3) {
    if (i >= n4big) return;
    s = by == 0 ? q : by == 1 ? k : v;
    d = by == 0 ? qd : by == 1 ? kd : vd;
  } else {
    if (i >= 4 * 262144) return;
    const int wsel = i >> 18;
    s = wsel == 0 ? W0 : wsel == 1 ? W1 : wsel == 2 ? W2 : W3;
    d = wsel == 0 ? W0d : wsel == 1 ? W1d : wsel == 2 ? W2d : W3d;
    i &= 262143;
  }
  float4 f = reinterpret_cast<const float4*>(s)[i];
  s16x4 o;
  o[0] = (short)f2bf(f.x); o[1] = (short)f2bf(f.y);
  o[2] = (short)f2bf(f.z); o[3] = (short)f2bf(f.w);
  reinterpret_cast<s16x4*>(d)[i] = o;
}

// XCD remap for 64x8 tile grids: xcd = wg&7 owns rows [8*xcd,8*xcd+8) x all
// 8 cols -> per-XCD working set A 2MB + B 2MB = its 4MB L2. Bijective.
__device__ __forceinline__ void xcd_tile(int wg, int& brow, int& bcol) {
  const int xcd = wg & 7, idx = wg >> 3;
  brow = ((xcd << 3) + (idx & 7)) * 128;
  bcol = (idx >> 3) * 128;
}

// C[M,N] = A[M,K] @ B[N,K]^T, all bf16 (C bf16 out), optional bias+relu.
// 128x128 tile, BK=32, 4 waves (2x2), 4x4 16x16x32 frags per wave.
template<int RELU_BIAS>
__global__ __launch_bounds__(256) void gemm_bt(
    const unsigned short* __restrict__ A, const unsigned short* __restrict__ B,
    unsigned short* __restrict__ C, const float* __restrict__ bias,
    int M, int N, int K) {
  __shared__ __align__(16) unsigned short As[128 * 32];
  __shared__ __align__(16) unsigned short Bs[128 * 32];
  const int tid = threadIdx.x;
  const int lane = tid & 63;
  const int w = tid >> 6;
  int brow, bcol;
  xcd_tile(blockIdx.x + (blockIdx.y << 6), brow, bcol);
  const int wr = (w >> 1) * 64;
  const int wc = (w & 1) * 64;

  f32x4 acc[4][4] = {};

  const int srow = w * 32 + (lane >> 2);  // + j*16
  const int scol = (lane & 3) * 8;
  const int rfrag = lane & 15;
  const int kfrag = (lane >> 4) * 8;

  for (int k0 = 0; k0 < K; k0 += 32) {
    __syncthreads();
#pragma unroll
    for (int j = 0; j < 2; ++j) {
      const unsigned short* ga = A + (size_t)(brow + srow + j * 16) * K + k0 + scol;
      gload_lds16(ga, As + (w * 1024 + j * 512));
      const unsigned short* gb = B + (size_t)(bcol + srow + j * 16) * K + k0 + scol;
      gload_lds16(gb, Bs + (w * 1024 + j * 512));
    }
    asm volatile("s_waitcnt vmcnt(0)" ::: "memory");
    __syncthreads();
    s16x8 a[4], b[4];
#pragma unroll
    for (int m = 0; m < 4; ++m)
      a[m] = *(const s16x8*)(As + (wr + m * 16 + rfrag) * 32 + kfrag);
#pragma unroll
    for (int n = 0; n < 4; ++n)
      b[n] = *(const s16x8*)(Bs + (wc + n * 16 + rfrag) * 32 + kfrag);
#pragma unroll
    for (int m = 0; m < 4; ++m)
#pragma unroll
      for (int n = 0; n < 4; ++n)
        acc[m][n] = __builtin_amdgcn_mfma_f32_16x16x32_bf16(a[m], b[n], acc[m][n], 0, 0, 0);
  }

  const int crow = brow + wr + ((lane >> 4) * 4);
  const int ccol = bcol + wc + (lane & 15);
  float bv[4];
  if (RELU_BIAS) {
#pragma unroll
    for (int n = 0; n < 4; ++n) bv[n] = bias[ccol + n * 16];
  }
#pragma unroll
  for (int m = 0; m < 4; ++m)
#pragma unroll
    for (int n = 0; n < 4; ++n)
#pragma unroll
      for (int r = 0; r < 4; ++r) {
        float vv = acc[m][n][r];
        if (RELU_BIAS) vv = fmaxf(vv + bv[n], 0.f);
        C[(size_t)(crow + m * 16 + r) * N + ccol + n * 16] = f2bf(vv);
      }
}

// 3 projection GEMMs in one dispatch; blockIdx.z selects (A,B,C) triple.
__global__ __launch_bounds__(256) void gemm_proj3(
    const unsigned short* __restrict__ A0, const unsigned short* __restrict__ A1,
    const unsigned short* __restrict__ A2, const unsigned short* __restrict__ B0,
    const unsigned short* __restrict__ B1, const unsigned short* __restrict__ B2,
    unsigned short* __restrict__ C0, unsigned short* __restrict__ C1,
    unsigned short* __restrict__ C2, int M, int N, int K) {
  const int z = blockIdx.z;
  const unsigned short* __restrict__ A = z == 0 ? A0 : z == 1 ? A1 : A2;
  const unsigned short* __restrict__ B = z == 0 ? B0 : z == 1 ? B1 : B2;
  unsigned short* __restrict__ C = z == 0 ? C0 : z == 1 ? C1 : C2;

  __shared__ __align__(16) unsigned short As[128 * 32];
  __shared__ __align__(16) unsigned short Bs[128 * 32];
  const int tid = threadIdx.x;
  const int lane = tid & 63;
  const int w = tid >> 6;
  int brow, bcol;
  xcd_tile(blockIdx.x + (blockIdx.y << 6), brow, bcol);
  const int wr = (w >> 1) * 64;
  const int wc = (w & 1) * 64;

  f32x4 acc[4][4] = {};

  const int srow = w * 32 + (lane >> 2);
  const int scol = (lane & 3) * 8;
  const int rfrag = lane & 15;
  const int kfrag = (lane >> 4) * 8;

  for (int k0 = 0; k0 < K; k0 += 32) {
    __syncthreads();
#pragma unroll
    for (int j = 0; j < 2; ++j) {
      const unsigned short* ga = A + (size_t)(brow + srow + j * 16) * K + k0 + scol;
      gload_lds16(ga, As + (w * 1024 + j * 512));
      const unsigned short* gb = B + (size_t)(bcol + srow + j * 16) * K + k0 + scol;
      gload_lds16(gb, Bs + (w * 1024 + j * 512));
    }
    asm volatile("s_waitcnt vmcnt(0)" ::: "memory");
    __syncthreads();
    s16x8 a[4], b[4];
#pragma unroll
    for (int m = 0; m < 4; ++m)
      a[m] = *(const s16x8*)(As + (wr + m * 16 + rfrag) * 32 + kfrag);
#pragma unroll
    for (int n = 0; n < 4; ++n)
      b[n] = *(const s16x8*)(Bs + (wc + n * 16 + rfrag) * 32 + kfrag);
#pragma unroll
    for (int m = 0; m < 4; ++m)
#pragma unroll
      for (int n = 0; n < 4; ++n)
        acc[m][n] = __builtin_amdgcn_mfma_f32_16x16x32_bf16(a[m], b[n], acc[m][n], 0, 0, 0);
  }

  const int crow = brow + wr + ((lane >> 4) * 4);
  const int ccol = bcol + wc + (lane & 15);
#pragma unroll
  for (int m = 0; m < 4; ++m)
#pragma unroll
    for (int n = 0; n < 4; ++n)
#pragma unroll
      for (int r = 0; r < 4; ++r)
        C[(size_t)(crow + m * 16 + r) * N + ccol + n * 16] = f2bf(acc[m][n][r]);
}

// Flash attention on 32x32x16 MFMA (round-14 exact). Grid 512 (16 q-tiles x
// 32 bh), 256 thr (4 waves x 32 q-rows). XCD remap: xcd = L&7 owns bh in
// [4*xcd, 4*xcd+4).
// LDS (u16): Ks [0,8192) [64][128] col-XOR-swizzled rows;
//            Vs [8192,16384) subtiled [k/4][d/16][4][16].
// smaskF: f32[2048] additive mask. Q [128][128] staged in Ks+Vs pre-loop.
// Swapped QK^T: S^T = mfma32(Kfrag, Qfrag): lane owns q = lane&31;
// k rows = kb*32 + (reg&3) + 8*(reg>>2) + 4*(lane>>5). Softmax in-lane.
// P->PV A-frags in-register: cvt_pk + v_permlane32_swap_b32 (T12).
__global__ __launch_bounds__(256, 2) void attn_fused(
    const unsigned short* __restrict__ Qp, const unsigned short* __restrict__ Kp,
    const unsigned short* __restrict__ Vp, const int* __restrict__ mask,
    unsigned short* __restrict__ Att) {
  constexpr int DD = 1024, NK = 2048;
  __shared__ __align__(16) unsigned short lds[16384];
  __shared__ __align__(16) float smaskF[2048];
  unsigned short* Ks = lds;
  unsigned short* Vs = lds + 8192;

  const int tid = threadIdx.x, lane = tid & 63, w = tid >> 6;
  const int quad = lane >> 4, lq = lane & 15;
  const int hi = lane >> 5, q5 = lane & 31;
  const int L = blockIdx.x;
  const int bh = (L & 7) * 4 + (L >> 7);   // 4 heads per XCD
  const int qt = (L >> 3) & 15;
  const int b = bh >> 3, h = bh & 7;
  const int q0 = qt * 128;
  const unsigned short* Qbase = Qp + ((size_t)b * 2048 + q0) * DD + h * 128;
  const unsigned short* Kbase = Kp + (size_t)b * 2048 * DD + h * 128;
  const unsigned short* Vbase = Vp + (size_t)b * 2048 * DD + h * 128;

  // ---- stage Q tile [128][128] (linear, Ks+Vs area) then hoist frags ----
#pragma unroll
  for (int j = 0; j < 8; ++j) {
    int row = w * 32 + j * 4 + quad;
    const unsigned short* g = Qbase + (size_t)row * DD + lq * 8;
    gload_lds16(g, lds + w * 4096 + j * 512);
  }
  asm volatile("s_waitcnt vmcnt(0)" ::: "memory");
  __syncthreads();
  // B-frag for mfma32: lane holds Q[q = q5 (+w*32)][d = ds*16 + hi*8 + j]
  s16x8 qf[8];
#pragma unroll
  for (int ds = 0; ds < 8; ++ds)
    qf[ds] = *(const s16x8*)(lds + (w * 32 + q5) * 128 + ds * 16 + hi * 8);

  // ---- preload full additive mask row -> smaskF ----
  {
    const int4* mp = (const int4*)(mask + b * NK);
    int4 m0 = mp[tid];
    int4 m1 = mp[tid + 256];
    f32x4 w0, w1;
    w0[0] = m0.x ? -1e30f : 0.f; w0[1] = m0.y ? -1e30f : 0.f;
    w0[2] = m0.z ? -1e30f : 0.f; w0[3] = m0.w ? -1e30f : 0.f;
    w1[0] = m1.x ? -1e30f : 0.f; w1[1] = m1.y ? -1e30f : 0.f;
    w1[2] = m1.z ? -1e30f : 0.f; w1[3] = m1.w ? -1e30f : 0.f;
    *(f32x4*)(smaskF + 4 * tid) = w0;
    *(f32x4*)(smaskF + 4 * (tid + 256)) = w1;
  }

  const unsigned vb0 = lds_off(Vs);
  const int swzq = (q5 & 7) << 4;

  f32x16 o[4] = {};
  float mrow = -1e30f, lrow = 0.f;

  for (int kt = 0; kt < NK / 64; ++kt) {
    const int k0 = kt * 64;
    __syncthreads();  // prior iteration's LDS reads done before overwrite
    // stage K [64][128] with XOR-swizzled SOURCE (linear LDS dest)
#pragma unroll
    for (int j = 0; j < 4; ++j) {
      int row = w * 16 + j * 4 + quad;
      int cb = lq * 16;                      // byte chunk within 256B row
      int cbs = cb ^ ((row & 7) << 4);       // involution on bits 4..6
      const unsigned short* g = Kbase + (size_t)(k0 + row) * DD + (cbs >> 1);
      gload_lds16(g, Ks + w * 2048 + j * 512);
    }
    // stage V into subtile layout [k/4][d/16][4][16] via pre-swizzled source
#pragma unroll
    for (int it = 0; it < 4; ++it) {
      int s = w * 256 + it * 64 + lane;
      int kk = ((s >> 6) << 2) | ((s >> 1) & 3);
      int dd = (((s >> 3) & 7) << 4) | ((s & 1) << 3);
      const unsigned short* g = Vbase + (size_t)(k0 + kk) * DD + dd;
      gload_lds16(g, Vs + (size_t)(w * 256 + it * 64) * 8);
    }
    asm volatile("s_waitcnt vmcnt(0)" ::: "memory");
    __syncthreads();

    // ---- S^T = (K Q^T)/32 + mask ----
    f32x16 acc0 = {}, acc1 = {};
    __builtin_amdgcn_s_setprio(1);
#pragma unroll
    for (int ds = 0; ds < 8; ++ds) {
      int cbs = (ds * 32 + hi * 16) ^ swzq;  // row&7 == q5&7 for both kb
      s16x8 kf0 = *(const s16x8*)((const char*)Ks + q5 * 256 + cbs);
      s16x8 kf1 = *(const s16x8*)((const char*)Ks + (q5 + 32) * 256 + cbs);
      acc0 = __builtin_amdgcn_mfma_f32_32x32x16_bf16(kf0, qf[ds], acc0, 0, 0, 0);
      acc1 = __builtin_amdgcn_mfma_f32_32x32x16_bf16(kf1, qf[ds], acc1, 0, 0, 0);
    }
    __builtin_amdgcn_s_setprio(0);

    // scale + mask; reg -> k = kb*32 + (reg&3) + 8*(reg>>2) + 4*hi
    float sv0[16], sv1[16];
#pragma unroll
    for (int g2 = 0; g2 < 4; ++g2) {
      f32x4 m0 = *(const f32x4*)(smaskF + k0 + g2 * 8 + hi * 4);
      f32x4 m1 = *(const f32x4*)(smaskF + k0 + 32 + g2 * 8 + hi * 4);
#pragma unroll
      for (int j2 = 0; j2 < 4; ++j2) {
        sv0[g2 * 4 + j2] = fmaf(acc0[g2 * 4 + j2], 0.03125f, m0[j2]);
        sv1[g2 * 4 + j2] = fmaf(acc1[g2 * 4 + j2], 0.03125f, m1[j2]);
      }
    }

    // ---- online softmax, in-lane over 32 values + one shfl ----
    float tm = fmaxf(sv0[0], sv1[0]);
#pragma unroll
    for (int r = 1; r < 16; ++r) tm = fmaxf(tm, fmaxf(sv0[r], sv1[r]));
    tm = fmaxf(tm, __shfl_xor(tm, 32, 64));
    // T13 defer-max
    const bool up = !__all(tm - mrow <= 8.f);
    float al = 1.f;
    if (up) {
      float mn = fmaxf(mrow, tm);
      al = __expf(mrow - mn);
      mrow = mn;
    }
    // ---- P = exp(S - m); build PV A-frags in-register (T12) ----
    float rs = 0.f;
    s16x8 pa[4];
    auto packP = [&](const float (&sv)[16], s16x8* paOut) {
      float p[16];
#pragma unroll
      for (int r = 0; r < 16; ++r) {
        p[r] = __expf(sv[r] - mrow);
        rs += p[r];
      }
#pragma unroll
      for (int i2 = 0; i2 < 2; ++i2) {
        unsigned a0, b0, a1, b1;
        asm("v_cvt_pk_bf16_f32 %0, %1, %2" : "=v"(a0) : "v"(p[i2 * 8 + 0]), "v"(p[i2 * 8 + 1]));
        asm("v_cvt_pk_bf16_f32 %0, %1, %2" : "=v"(b0) : "v"(p[i2 * 8 + 4]), "v"(p[i2 * 8 + 5]));
        asm("v_cvt_pk_bf16_f32 %0, %1, %2" : "=v"(a1) : "v"(p[i2 * 8 + 2]), "v"(p[i2 * 8 + 3]));
        asm("v_cvt_pk_bf16_f32 %0, %1, %2" : "=v"(b1) : "v"(p[i2 * 8 + 6]), "v"(p[i2 * 8 + 7]));
        asm volatile("v_permlane32_swap_b32 %0, %1" : "+v"(a0), "+v"(b0));
        asm volatile("v_permlane32_swap_b32 %0, %1" : "+v"(a1), "+v"(b1));
        u32x4 wv;
        wv[0] = a0; wv[1] = a1; wv[2] = b0; wv[3] = b1;
        paOut[i2] = *(s16x8*)&wv;
      }
    };
    packP(sv0, &pa[0]);
    packP(sv1, &pa[2]);
    rs += __shfl_xor(rs, 32, 64);
    lrow = lrow * al + rs;
    if (up) {
#pragma unroll
      for (int reg = 0; reg < 16; ++reg) {
        float alo = __shfl(al, (reg & 3) + 8 * (reg >> 2) + 4 * hi, 64);
#pragma unroll
        for (int db = 0; db < 4; ++db) o[db][reg] *= alo;
      }
    }

    // ---- O += P V (pa in regs; V via ds_read_b64_tr_b16) ----
#pragma unroll
    for (int db = 0; db < 4; ++db) {
      s16x4 vlo[4], vhi[4];
#pragma unroll
      for (int kb2 = 0; kb2 < 4; ++kb2) {
        const unsigned va = vb0 + (kb2 * 4 + hi * 2) * 1024 +
                            (db * 2 + (quad & 1)) * 128 + lq * 8;
        asm volatile("ds_read_b64_tr_b16 %0, %2\n\t"
                     "ds_read_b64_tr_b16 %1, %2 offset:1024"
                     : "=&v"(vlo[kb2]), "=&v"(vhi[kb2])
                     : "v"(va)
                     : "memory");
      }
      asm volatile("s_waitcnt lgkmcnt(0)" ::: "memory");
      __builtin_amdgcn_sched_barrier(0);
      __builtin_amdgcn_s_setprio(1);
#pragma unroll
      for (int kb2 = 0; kb2 < 4; ++kb2) {
        s16x8 vv;
#pragma unroll
        for (int j = 0; j < 4; ++j) { vv[j] = vlo[kb2][j]; vv[4 + j] = vhi[kb2][j]; }
        o[db] = __builtin_amdgcn_mfma_f32_32x32x16_bf16(pa[kb2], vv, o[db], 0, 0, 0);
      }
      __builtin_amdgcn_s_setprio(0);
    }
  }

  // ---- normalize + write ----
  float inv = (mrow <= -1e29f || lrow <= 0.f) ? 0.f : 1.f / lrow;
#pragma unroll
  for (int reg = 0; reg < 16; ++reg) {
    const int rown = (reg & 3) + 8 * (reg >> 2) + 4 * hi;
    float invo = __shfl(inv, rown, 64);
    const int q = q0 + w * 32 + rown;
#pragma unroll
    for (int db = 0; db < 4; ++db) {
      Att[((size_t)b * 2048 + q) * DD + h * 128 + db * 32 + q5] =
          f2bf(o[db][reg] * invo);
    }
  }
}

// out = LayerNorm(X + Y) * g + b. One block per 1024-elem row.
template<int OUT_F32>
__global__ __launch_bounds__(256) void add_ln(
    const unsigned short* __restrict__ X, const unsigned short* __restrict__ Y,
    const float* __restrict__ gam, const float* __restrict__ bet,
    void* __restrict__ out) {
  const int row = blockIdx.x;
  const int tid = threadIdx.x;
  const int lane = tid & 63, w = tid >> 6;
  __shared__ float rbuf[8];
  const size_t base = (size_t)row * 1024 + tid * 4;
  s16x4 xa = *(const s16x4*)(X + base);
  s16x4 yb = *(const s16x4*)(Y + base);
  float x[4];
  float s1 = 0.f, s2 = 0.f;
#pragma unroll
  for (int j = 0; j < 4; ++j) {
    x[j] = bf2f((unsigned short)xa[j]) + bf2f((unsigned short)yb[j]);
    s1 += x[j];
    s2 += x[j] * x[j];
  }
#pragma unroll
  for (int d = 1; d < 64; d <<= 1) {
    s1 += __shfl_xor(s1, d, 64);
    s2 += __shfl_xor(s2, d, 64);
  }
  if (lane == 0) { rbuf[w] = s1; rbuf[4 + w] = s2; }
  __syncthreads();
  float t1 = rbuf[0] + rbuf[1] + rbuf[2] + rbuf[3];
  float t2 = rbuf[4] + rbuf[5] + rbuf[6] + rbuf[7];
  float mu = t1 * (1.f / 1024.f);
  float var = t2 * (1.f / 1024.f) - mu * mu;
  float rstd = rsqrtf(fmaxf(var, 0.f) + 1e-5f);
  float4 g4 = *(const float4*)(gam + tid * 4);
  float4 b4 = *(const float4*)(bet + tid * 4);
  float gg[4] = {g4.x, g4.y, g4.z, g4.w};
  float bb[4] = {b4.x, b4.y, b4.z, b4.w};
  if (OUT_F32) {
    float4 o4;
    o4.x = (x[0] - mu) * rstd * gg[0] + bb[0];
    o4.y = (x[1] - mu) * rstd * gg[1] + bb[1];
    o4.z = (x[2] - mu) * rstd * gg[2] + bb[2];
    o4.w = (x[3] - mu) * rstd * gg[3] + bb[3];
    *(float4*)((float*)out + base) = o4;
  } else {
    s16x4 o;
#pragma unroll
    for (int j = 0; j < 4; ++j)
      o[j] = (short)f2bf((x[j] - mu) * rstd * gg[j] + bb[j]);
    *(s16x4*)((unsigned short*)out + base) = o;
  }
}

extern "C" void kernel_launch(void* const* d_in, const int* in_sizes, int n_in,
                              void* d_out, int out_size, void* d_ws, size_t ws_size,
                              hipStream_t stream) {
  const float* q  = (const float*)d_in[0];
  const float* k  = (const float*)d_in[1];
  const float* v  = (const float*)d_in[2];
  const int* msk  = (const int*)d_in[3];
  const float* Wq = (const float*)d_in[4];
  const float* Wk = (const float*)d_in[5];
  const float* Wv = (const float*)d_in[6];
  const float* Wo = (const float*)d_in[7];
  const float* bo = (const float*)d_in[8];
  const float* g1 = (const float*)d_in[9];
  const float* b1 = (const float*)d_in[10];
  const float* g2 = (const float*)d_in[11];
  const float* b2 = (const float*)d_in[12];
  float* out = (float*)d_out;

  char* ws = (char*)d_ws;
  const size_t S = (size_t)8192 * 1024 * 2;
  unsigned short* qb  = (unsigned short*)(ws + 0 * S);
  unsigned short* kb  = (unsigned short*)(ws + 1 * S);
  unsigned short* vb  = (unsigned short*)(ws + 2 * S);
  unsigned short* qpb = (unsigned short*)(ws + 3 * S);
  unsigned short* kpb = (unsigned short*)(ws + 4 * S);
  unsigned short* vpb = (unsigned short*)(ws + 5 * S);
  unsigned short* attb = qb;  // reuse: q bf16 dead after proj
  unsigned short* h1b  = kb;
  unsigned short* h2b  = vb;
  unsigned short* Wqb = (unsigned short*)(ws + 6 * S);
  unsigned short* Wkb = Wqb + (size_t)1024 * 1024;
  unsigned short* Wvb = Wkb + (size_t)1024 * 1024;
  unsigned short* Wob = Wvb + (size_t)1024 * 1024;

  const int n4big = 8192 * 1024 / 4;
  cvt_fused<<<dim3(8192, 4), 256, 0, stream>>>(
      q, k, v, Wq, Wk, Wv, Wo, qb, kb, vb, Wqb, Wkb, Wvb, Wob, n4big);

  gemm_proj3<<<dim3(64, 8, 3), 256, 0, stream>>>(
      qb, kb, vb, Wqb, Wkb, Wvb, qpb, kpb, vpb, 8192, 1024, 1024);

  attn_fused<<<512, 256, 0, stream>>>(qpb, kpb, vpb, msk, attb);

  add_ln<0><<<8192, 256, 0, stream>>>(qpb, attb, g1, b1, (void*)h1b);
  gemm_bt<1><<<dim3(64, 8), 256, 0, stream>>>(h1b, Wob, h2b, bo, 8192, 1024, 1024);
  add_ln<1><<<8192, 256, 0, stream>>>(h1b, h2b, g2, b2, (void*)out);
}

// Round 17
// 217.186 us; speedup vs baseline: 1.1501x; 1.0832x over previous
//
#include <hip/hip_runtime.h>

// MultiHeadAttn fused block, MI355X/gfx950.
// Round 17: q/k/v f32->bf16 convert pass ELIMINATED (was 144MB ~23us).
// gemm_proj3 now reads f32 A directly: A staged as f32 via gload_lds into
// XOR-swizzled LDS (128B rows = G4 conflict case; pre-swizzled source,
// same involution as attn K path), frags converted in-register with
// v_cvt_pk_bf16_f32. cvt kernel reduced to the 4 weights (8MB).
// attn (round-14, 100us) and gemm_bt<1> unchanged. XCD remap kept (neutral).

typedef __attribute__((ext_vector_type(4))) float f32x4;
typedef __attribute__((ext_vector_type(16))) float f32x16;
typedef __attribute__((ext_vector_type(8))) short s16x8;
typedef __attribute__((ext_vector_type(4))) short s16x4;
typedef __attribute__((ext_vector_type(4))) unsigned int u32x4;

__device__ __forceinline__ unsigned short f2bf(float f) {
  union { float f; unsigned u; } x; x.f = f;
  unsigned r = x.u + 0x7fffu + ((x.u >> 16) & 1u);
  return (unsigned short)(r >> 16);
}
__device__ __forceinline__ float bf2f(unsigned short h) {
  union { unsigned u; float f; } x; x.u = ((unsigned)h) << 16;
  return x.f;
}

__device__ __forceinline__ void gload_lds16(const void* g, void* l) {
  __builtin_amdgcn_global_load_lds(
      (const __attribute__((address_space(1))) unsigned int*)g,
      (__attribute__((address_space(3))) unsigned int*)l, 16, 0, 0);
}

__device__ __forceinline__ unsigned lds_off(const void* p) {
  return (unsigned)(size_t)(const __attribute__((address_space(3))) void*)p;
}

// Weights-only convert: 4 x (1024x1024) f32 -> bf16; wsel = i>>18.
__global__ __launch_bounds__(256) void cvt_w(
    const float* __restrict__ W0, const float* __restrict__ W1,
    const float* __restrict__ W2, const float* __restrict__ W3,
    unsigned short* __restrict__ W0d, unsigned short* __restrict__ W1d,
    unsigned short* __restrict__ W2d, unsigned short* __restrict__ W3d) {
  int i = blockIdx.x * blockDim.x + threadIdx.x;
  const int wsel = i >> 18;
  const float* s = wsel == 0 ? W0 : wsel == 1 ? W1 : wsel == 2 ? W2 : W3;
  unsigned short* d = wsel == 0 ? W0d : wsel == 1 ? W1d : wsel == 2 ? W2d : W3d;
  i &= 262143;
  float4 f = reinterpret_cast<const float4*>(s)[i];
  s16x4 o;
  o[0] = (short)f2bf(f.x); o[1] = (short)f2bf(f.y);
  o[2] = (short)f2bf(f.z); o[3] = (short)f2bf(f.w);
  reinterpret_cast<s16x4*>(d)[i] = o;
}

// XCD remap for 64x8 tile grids: xcd = wg&7 owns rows [8*xcd,8*xcd+8) x all
// 8 cols -> per-XCD working set fits its 4MB L2. Bijective.
__device__ __forceinline__ void xcd_tile(int wg, int& brow, int& bcol) {
  const int xcd = wg & 7, idx = wg >> 3;
  brow = ((xcd << 3) + (idx & 7)) * 128;
  bcol = (idx >> 3) * 128;
}

// C[M,N] = A[M,K] @ B[N,K]^T, bf16 A/B (C bf16), optional bias+relu.
// 128x128 tile, BK=32, 4 waves (2x2), 4x4 16x16x32 frags per wave.
template<int RELU_BIAS>
__global__ __launch_bounds__(256) void gemm_bt(
    const unsigned short* __restrict__ A, const unsigned short* __restrict__ B,
    unsigned short* __restrict__ C, const float* __restrict__ bias,
    int M, int N, int K) {
  __shared__ __align__(16) unsigned short As[128 * 32];
  __shared__ __align__(16) unsigned short Bs[128 * 32];
  const int tid = threadIdx.x;
  const int lane = tid & 63;
  const int w = tid >> 6;
  int brow, bcol;
  xcd_tile(blockIdx.x + (blockIdx.y << 6), brow, bcol);
  const int wr = (w >> 1) * 64;
  const int wc = (w & 1) * 64;

  f32x4 acc[4][4] = {};

  const int srow = w * 32 + (lane >> 2);  // + j*16
  const int scol = (lane & 3) * 8;
  const int rfrag = lane & 15;
  const int kfrag = (lane >> 4) * 8;

  for (int k0 = 0; k0 < K; k0 += 32) {
    __syncthreads();
#pragma unroll
    for (int j = 0; j < 2; ++j) {
      const unsigned short* ga = A + (size_t)(brow + srow + j * 16) * K + k0 + scol;
      gload_lds16(ga, As + (w * 1024 + j * 512));
      const unsigned short* gb = B + (size_t)(bcol + srow + j * 16) * K + k0 + scol;
      gload_lds16(gb, Bs + (w * 1024 + j * 512));
    }
    asm volatile("s_waitcnt vmcnt(0)" ::: "memory");
    __syncthreads();
    s16x8 a[4], b[4];
#pragma unroll
    for (int m = 0; m < 4; ++m)
      a[m] = *(const s16x8*)(As + (wr + m * 16 + rfrag) * 32 + kfrag);
#pragma unroll
    for (int n = 0; n < 4; ++n)
      b[n] = *(const s16x8*)(Bs + (wc + n * 16 + rfrag) * 32 + kfrag);
#pragma unroll
    for (int m = 0; m < 4; ++m)
#pragma unroll
      for (int n = 0; n < 4; ++n)
        acc[m][n] = __builtin_amdgcn_mfma_f32_16x16x32_bf16(a[m], b[n], acc[m][n], 0, 0, 0);
  }

  const int crow = brow + wr + ((lane >> 4) * 4);
  const int ccol = bcol + wc + (lane & 15);
  float bv[4];
  if (RELU_BIAS) {
#pragma unroll
    for (int n = 0; n < 4; ++n) bv[n] = bias[ccol + n * 16];
  }
#pragma unroll
  for (int m = 0; m < 4; ++m)
#pragma unroll
    for (int n = 0; n < 4; ++n)
#pragma unroll
      for (int r = 0; r < 4; ++r) {
        float vv = acc[m][n][r];
        if (RELU_BIAS) vv = fmaxf(vv + bv[n], 0.f);
        C[(size_t)(crow + m * 16 + r) * N + ccol + n * 16] = f2bf(vv);
      }
}

// 3 projection GEMMs, f32 A / bf16 B; blockIdx.z selects the triple.
// A staged as f32 [128][32] XOR-swizzled (rows 128B; source pre-swizzle
// cb ^ ((row&7)<<4)); frags converted in-register via v_cvt_pk_bf16_f32.
__global__ __launch_bounds__(256) void gemm_proj3(
    const float* __restrict__ A0, const float* __restrict__ A1,
    const float* __restrict__ A2, const unsigned short* __restrict__ B0,
    const unsigned short* __restrict__ B1, const unsigned short* __restrict__ B2,
    unsigned short* __restrict__ C0, unsigned short* __restrict__ C1,
    unsigned short* __restrict__ C2, int M, int N, int K) {
  const int z = blockIdx.z;
  const float* __restrict__ A = z == 0 ? A0 : z == 1 ? A1 : A2;
  const unsigned short* __restrict__ B = z == 0 ? B0 : z == 1 ? B1 : B2;
  unsigned short* __restrict__ C = z == 0 ? C0 : z == 1 ? C1 : C2;

  __shared__ __align__(16) float Asf[128 * 32];       // 16 KB, swizzled
  __shared__ __align__(16) unsigned short Bs[128 * 32];
  const int tid = threadIdx.x;
  const int lane = tid & 63;
  const int w = tid >> 6;
  int brow, bcol;
  xcd_tile(blockIdx.x + (blockIdx.y << 6), brow, bcol);
  const int wr = (w >> 1) * 64;
  const int wc = (w & 1) * 64;

  f32x4 acc[4][4] = {};

  // B staging (bf16, unchanged pattern)
  const int srow = w * 32 + (lane >> 2);  // + j*16
  const int scol = (lane & 3) * 8;
  // A staging (f32): issue j covers rows w*32+j*8 + (lane>>3); 16B chunk
  // (lane&7) within the 128B row, source-preswizzled.
  const int arow = w * 32 + (lane >> 3);  // + j*8
  const int acb = (lane & 7) * 16;        // byte chunk within 128B row
  const int rfrag = lane & 15;
  const int quad = lane >> 4;

  for (int k0 = 0; k0 < K; k0 += 32) {
    __syncthreads();
#pragma unroll
    for (int j = 0; j < 2; ++j) {
      const unsigned short* gb = B + (size_t)(bcol + srow + j * 16) * K + k0 + scol;
      gload_lds16(gb, Bs + (w * 1024 + j * 512));
    }
#pragma unroll
    for (int j = 0; j < 4; ++j) {
      int row = arow + j * 8;
      int cbs = acb ^ ((row & 7) << 4);
      const float* ga = A + (size_t)(brow + row) * K + k0 + (cbs >> 2);
      gload_lds16(ga, (char*)Asf + w * 4096 + j * 1024);
    }
    asm volatile("s_waitcnt vmcnt(0)" ::: "memory");
    __syncthreads();
    s16x8 a[4], b[4];
#pragma unroll
    for (int m = 0; m < 4; ++m) {
      const int r = wr + m * 16 + rfrag;
      const int b1 = (quad * 32) ^ ((r & 7) << 4);
      const int b2 = (quad * 32 + 16) ^ ((r & 7) << 4);
      f32x4 a0 = *(const f32x4*)((const char*)Asf + r * 128 + b1);
      f32x4 a1 = *(const f32x4*)((const char*)Asf + r * 128 + b2);
      unsigned w0, w1, w2, w3;
      asm("v_cvt_pk_bf16_f32 %0, %1, %2" : "=v"(w0) : "v"(a0[0]), "v"(a0[1]));
      asm("v_cvt_pk_bf16_f32 %0, %1, %2" : "=v"(w1) : "v"(a0[2]), "v"(a0[3]));
      asm("v_cvt_pk_bf16_f32 %0, %1, %2" : "=v"(w2) : "v"(a1[0]), "v"(a1[1]));
      asm("v_cvt_pk_bf16_f32 %0, %1, %2" : "=v"(w3) : "v"(a1[2]), "v"(a1[3]));
      u32x4 wv; wv[0] = w0; wv[1] = w1; wv[2] = w2; wv[3] = w3;
      a[m] = *(s16x8*)&wv;
    }
#pragma unroll
    for (int n = 0; n < 4; ++n)
      b[n] = *(const s16x8*)(Bs + (wc + n * 16 + rfrag) * 32 + quad * 8);
#pragma unroll
    for (int m = 0; m < 4; ++m)
#pragma unroll
      for (int n = 0; n < 4; ++n)
        acc[m][n] = __builtin_amdgcn_mfma_f32_16x16x32_bf16(a[m], b[n], acc[m][n], 0, 0, 0);
  }

  const int crow = brow + wr + (quad * 4);
  const int ccol = bcol + wc + rfrag;
#pragma unroll
  for (int m = 0; m < 4; ++m)
#pragma unroll
    for (int n = 0; n < 4; ++n)
#pragma unroll
      for (int r = 0; r < 4; ++r)
        C[(size_t)(crow + m * 16 + r) * N + ccol + n * 16] = f2bf(acc[m][n][r]);
}

// Flash attention on 32x32x16 MFMA (round-14 exact). Grid 512 (16 q-tiles x
// 32 bh), 256 thr (4 waves x 32 q-rows). XCD remap: xcd = L&7 owns bh in
// [4*xcd, 4*xcd+4).
// LDS (u16): Ks [0,8192) [64][128] col-XOR-swizzled rows;
//            Vs [8192,16384) subtiled [k/4][d/16][4][16].
// smaskF: f32[2048] additive mask. Q [128][128] staged in Ks+Vs pre-loop.
// Swapped QK^T: S^T = mfma32(Kfrag, Qfrag): lane owns q = lane&31;
// k rows = kb*32 + (reg&3) + 8*(reg>>2) + 4*(lane>>5). Softmax in-lane.
// P->PV A-frags in-register: cvt_pk + v_permlane32_swap_b32 (T12).
__global__ __launch_bounds__(256, 2) void attn_fused(
    const unsigned short* __restrict__ Qp, const unsigned short* __restrict__ Kp,
    const unsigned short* __restrict__ Vp, const int* __restrict__ mask,
    unsigned short* __restrict__ Att) {
  constexpr int DD = 1024, NK = 2048;
  __shared__ __align__(16) unsigned short lds[16384];
  __shared__ __align__(16) float smaskF[2048];
  unsigned short* Ks = lds;
  unsigned short* Vs = lds + 8192;

  const int tid = threadIdx.x, lane = tid & 63, w = tid >> 6;
  const int quad = lane >> 4, lq = lane & 15;
  const int hi = lane >> 5, q5 = lane & 31;
  const int L = blockIdx.x;
  const int bh = (L & 7) * 4 + (L >> 7);   // 4 heads per XCD
  const int qt = (L >> 3) & 15;
  const int b = bh >> 3, h = bh & 7;
  const int q0 = qt * 128;
  const unsigned short* Qbase = Qp + ((size_t)b * 2048 + q0) * DD + h * 128;
  const unsigned short* Kbase = Kp + (size_t)b * 2048 * DD + h * 128;
  const unsigned short* Vbase = Vp + (size_t)b * 2048 * DD + h * 128;

  // ---- stage Q tile [128][128] (linear, Ks+Vs area) then hoist frags ----
#pragma unroll
  for (int j = 0; j < 8; ++j) {
    int row = w * 32 + j * 4 + quad;
    const unsigned short* g = Qbase + (size_t)row * DD + lq * 8;
    gload_lds16(g, lds + w * 4096 + j * 512);
  }
  asm volatile("s_waitcnt vmcnt(0)" ::: "memory");
  __syncthreads();
  // B-frag for mfma32: lane holds Q[q = q5 (+w*32)][d = ds*16 + hi*8 + j]
  s16x8 qf[8];
#pragma unroll
  for (int ds = 0; ds < 8; ++ds)
    qf[ds] = *(const s16x8*)(lds + (w * 32 + q5) * 128 + ds * 16 + hi * 8);

  // ---- preload full additive mask row -> smaskF ----
  {
    const int4* mp = (const int4*)(mask + b * NK);
    int4 m0 = mp[tid];
    int4 m1 = mp[tid + 256];
    f32x4 w0, w1;
    w0[0] = m0.x ? -1e30f : 0.f; w0[1] = m0.y ? -1e30f : 0.f;
    w0[2] = m0.z ? -1e30f : 0.f; w0[3] = m0.w ? -1e30f : 0.f;
    w1[0] = m1.x ? -1e30f : 0.f; w1[1] = m1.y ? -1e30f : 0.f;
    w1[2] = m1.z ? -1e30f : 0.f; w1[3] = m1.w ? -1e30f : 0.f;
    *(f32x4*)(smaskF + 4 * tid) = w0;
    *(f32x4*)(smaskF + 4 * (tid + 256)) = w1;
  }

  const unsigned vb0 = lds_off(Vs);
  const int swzq = (q5 & 7) << 4;

  f32x16 o[4] = {};
  float mrow = -1e30f, lrow = 0.f;

  for (int kt = 0; kt < NK / 64; ++kt) {
    const int k0 = kt * 64;
    __syncthreads();  // prior iteration's LDS reads done before overwrite
    // stage K [64][128] with XOR-swizzled SOURCE (linear LDS dest)
#pragma unroll
    for (int j = 0; j < 4; ++j) {
      int row = w * 16 + j * 4 + quad;
      int cb = lq * 16;                      // byte chunk within 256B row
      int cbs = cb ^ ((row & 7) << 4);       // involution on bits 4..6
      const unsigned short* g = Kbase + (size_t)(k0 + row) * DD + (cbs >> 1);
      gload_lds16(g, Ks + w * 2048 + j * 512);
    }
    // stage V into subtile layout [k/4][d/16][4][16] via pre-swizzled source
#pragma unroll
    for (int it = 0; it < 4; ++it) {
      int s = w * 256 + it * 64 + lane;
      int kk = ((s >> 6) << 2) | ((s >> 1) & 3);
      int dd = (((s >> 3) & 7) << 4) | ((s & 1) << 3);
      const unsigned short* g = Vbase + (size_t)(k0 + kk) * DD + dd;
      gload_lds16(g, Vs + (size_t)(w * 256 + it * 64) * 8);
    }
    asm volatile("s_waitcnt vmcnt(0)" ::: "memory");
    __syncthreads();

    // ---- S^T = (K Q^T)/32 + mask ----
    f32x16 acc0 = {}, acc1 = {};
    __builtin_amdgcn_s_setprio(1);
#pragma unroll
    for (int ds = 0; ds < 8; ++ds) {
      int cbs = (ds * 32 + hi * 16) ^ swzq;  // row&7 == q5&7 for both kb
      s16x8 kf0 = *(const s16x8*)((const char*)Ks + q5 * 256 + cbs);
      s16x8 kf1 = *(const s16x8*)((const char*)Ks + (q5 + 32) * 256 + cbs);
      acc0 = __builtin_amdgcn_mfma_f32_32x32x16_bf16(kf0, qf[ds], acc0, 0, 0, 0);
      acc1 = __builtin_amdgcn_mfma_f32_32x32x16_bf16(kf1, qf[ds], acc1, 0, 0, 0);
    }
    __builtin_amdgcn_s_setprio(0);

    // scale + mask; reg -> k = kb*32 + (reg&3) + 8*(reg>>2) + 4*hi
    float sv0[16], sv1[16];
#pragma unroll
    for (int g2 = 0; g2 < 4; ++g2) {
      f32x4 m0 = *(const f32x4*)(smaskF + k0 + g2 * 8 + hi * 4);
      f32x4 m1 = *(const f32x4*)(smaskF + k0 + 32 + g2 * 8 + hi * 4);
#pragma unroll
      for (int j2 = 0; j2 < 4; ++j2) {
        sv0[g2 * 4 + j2] = fmaf(acc0[g2 * 4 + j2], 0.03125f, m0[j2]);
        sv1[g2 * 4 + j2] = fmaf(acc1[g2 * 4 + j2], 0.03125f, m1[j2]);
      }
    }

    // ---- online softmax, in-lane over 32 values + one shfl ----
    float tm = fmaxf(sv0[0], sv1[0]);
#pragma unroll
    for (int r = 1; r < 16; ++r) tm = fmaxf(tm, fmaxf(sv0[r], sv1[r]));
    tm = fmaxf(tm, __shfl_xor(tm, 32, 64));
    // T13 defer-max
    const bool up = !__all(tm - mrow <= 8.f);
    float al = 1.f;
    if (up) {
      float mn = fmaxf(mrow, tm);
      al = __expf(mrow - mn);
      mrow = mn;
    }
    // ---- P = exp(S - m); build PV A-frags in-register (T12) ----
    float rs = 0.f;
    s16x8 pa[4];
    auto packP = [&](const float (&sv)[16], s16x8* paOut) {
      float p[16];
#pragma unroll
      for (int r = 0; r < 16; ++r) {
        p[r] = __expf(sv[r] - mrow);
        rs += p[r];
      }
#pragma unroll
      for (int i2 = 0; i2 < 2; ++i2) {
        unsigned a0, b0, a1, b1;
        asm("v_cvt_pk_bf16_f32 %0, %1, %2" : "=v"(a0) : "v"(p[i2 * 8 + 0]), "v"(p[i2 * 8 + 1]));
        asm("v_cvt_pk_bf16_f32 %0, %1, %2" : "=v"(b0) : "v"(p[i2 * 8 + 4]), "v"(p[i2 * 8 + 5]));
        asm("v_cvt_pk_bf16_f32 %0, %1, %2" : "=v"(a1) : "v"(p[i2 * 8 + 2]), "v"(p[i2 * 8 + 3]));
        asm("v_cvt_pk_bf16_f32 %0, %1, %2" : "=v"(b1) : "v"(p[i2 * 8 + 6]), "v"(p[i2 * 8 + 7]));
        asm volatile("v_permlane32_swap_b32 %0, %1" : "+v"(a0), "+v"(b0));
        asm volatile("v_permlane32_swap_b32 %0, %1" : "+v"(a1), "+v"(b1));
        u32x4 wv;
        wv[0] = a0; wv[1] = a1; wv[2] = b0; wv[3] = b1;
        paOut[i2] = *(s16x8*)&wv;
      }
    };
    packP(sv0, &pa[0]);
    packP(sv1, &pa[2]);
    rs += __shfl_xor(rs, 32, 64);
    lrow = lrow * al + rs;
    if (up) {
#pragma unroll
      for (int reg = 0; reg < 16; ++reg) {
        float alo = __shfl(al, (reg & 3) + 8 * (reg >> 2) + 4 * hi, 64);
#pragma unroll
        for (int db = 0; db < 4; ++db) o[db][reg] *= alo;
      }
    }

    // ---- O += P V (pa in regs; V via ds_read_b64_tr_b16) ----
#pragma unroll
    for (int db = 0; db < 4; ++db) {
      s16x4 vlo[4], vhi[4];
#pragma unroll
      for (int kb2 = 0; kb2 < 4; ++kb2) {
        const unsigned va = vb0 + (kb2 * 4 + hi * 2) * 1024 +
                            (db * 2 + (quad & 1)) * 128 + lq * 8;
        asm volatile("ds_read_b64_tr_b16 %0, %2\n\t"
                     "ds_read_b64_tr_b16 %1, %2 offset:1024"
                     : "=&v"(vlo[kb2]), "=&v"(vhi[kb2])
                     : "v"(va)
                     : "memory");
      }
      asm volatile("s_waitcnt lgkmcnt(0)" ::: "memory");
      __builtin_amdgcn_sched_barrier(0);
      __builtin_amdgcn_s_setprio(1);
#pragma unroll
      for (int kb2 = 0; kb2 < 4; ++kb2) {
        s16x8 vv;
#pragma unroll
        for (int j = 0; j < 4; ++j) { vv[j] = vlo[kb2][j]; vv[4 + j] = vhi[kb2][j]; }
        o[db] = __builtin_amdgcn_mfma_f32_32x32x16_bf16(pa[kb2], vv, o[db], 0, 0, 0);
      }
      __builtin_amdgcn_s_setprio(0);
    }
  }

  // ---- normalize + write ----
  float inv = (mrow <= -1e29f || lrow <= 0.f) ? 0.f : 1.f / lrow;
#pragma unroll
  for (int reg = 0; reg < 16; ++reg) {
    const int rown = (reg & 3) + 8 * (reg >> 2) + 4 * hi;
    float invo = __shfl(inv, rown, 64);
    const int q = q0 + w * 32 + rown;
#pragma unroll
    for (int db = 0; db < 4; ++db) {
      Att[((size_t)b * 2048 + q) * DD + h * 128 + db * 32 + q5] =
          f2bf(o[db][reg] * invo);
    }
  }
}

// out = LayerNorm(X + Y) * g + b. One block per 1024-elem row.
template<int OUT_F32>
__global__ __launch_bounds__(256) void add_ln(
    const unsigned short* __restrict__ X, const unsigned short* __restrict__ Y,
    const float* __restrict__ gam, const float* __restrict__ bet,
    void* __restrict__ out) {
  const int row = blockIdx.x;
  const int tid = threadIdx.x;
  const int lane = tid & 63, w = tid >> 6;
  __shared__ float rbuf[8];
  const size_t base = (size_t)row * 1024 + tid * 4;
  s16x4 xa = *(const s16x4*)(X + base);
  s16x4 yb = *(const s16x4*)(Y + base);
  float x[4];
  float s1 = 0.f, s2 = 0.f;
#pragma unroll
  for (int j = 0; j < 4; ++j) {
    x[j] = bf2f((unsigned short)xa[j]) + bf2f((unsigned short)yb[j]);
    s1 += x[j];
    s2 += x[j] * x[j];
  }
#pragma unroll
  for (int d = 1; d < 64; d <<= 1) {
    s1 += __shfl_xor(s1, d, 64);
    s2 += __shfl_xor(s2, d, 64);
  }
  if (lane == 0) { rbuf[w] = s1; rbuf[4 + w] = s2; }
  __syncthreads();
  float t1 = rbuf[0] + rbuf[1] + rbuf[2] + rbuf[3];
  float t2 = rbuf[4] + rbuf[5] + rbuf[6] + rbuf[7];
  float mu = t1 * (1.f / 1024.f);
  float var = t2 * (1.f / 1024.f) - mu * mu;
  float rstd = rsqrtf(fmaxf(var, 0.f) + 1e-5f);
  float4 g4 = *(const float4*)(gam + tid * 4);
  float4 b4 = *(const float4*)(bet + tid * 4);
  float gg[4] = {g4.x, g4.y, g4.z, g4.w};
  float bb[4] = {b4.x, b4.y, b4.z, b4.w};
  if (OUT_F32) {
    float4 o4;
    o4.x = (x[0] - mu) * rstd * gg[0] + bb[0];
    o4.y = (x[1] - mu) * rstd * gg[1] + bb[1];
    o4.z = (x[2] - mu) * rstd * gg[2] + bb[2];
    o4.w = (x[3] - mu) * rstd * gg[3] + bb[3];
    *(float4*)((float*)out + base) = o4;
  } else {
    s16x4 o;
#pragma unroll
    for (int j = 0; j < 4; ++j)
      o[j] = (short)f2bf((x[j] - mu) * rstd * gg[j] + bb[j]);
    *(s16x4*)((unsigned short*)out + base) = o;
  }
}

extern "C" void kernel_launch(void* const* d_in, const int* in_sizes, int n_in,
                              void* d_out, int out_size, void* d_ws, size_t ws_size,
                              hipStream_t stream) {
  const float* q  = (const float*)d_in[0];
  const float* k  = (const float*)d_in[1];
  const float* v  = (const float*)d_in[2];
  const int* msk  = (const int*)d_in[3];
  const float* Wq = (const float*)d_in[4];
  const float* Wk = (const float*)d_in[5];
  const float* Wv = (const float*)d_in[6];
  const float* Wo = (const float*)d_in[7];
  const float* bo = (const float*)d_in[8];
  const float* g1 = (const float*)d_in[9];
  const float* b1 = (const float*)d_in[10];
  const float* g2 = (const float*)d_in[11];
  const float* b2 = (const float*)d_in[12];
  float* out = (float*)d_out;

  char* ws = (char*)d_ws;
  const size_t S = (size_t)8192 * 1024 * 2;
  unsigned short* qpb = (unsigned short*)(ws + 3 * S);
  unsigned short* kpb = (unsigned short*)(ws + 4 * S);
  unsigned short* vpb = (unsigned short*)(ws + 5 * S);
  unsigned short* attb = (unsigned short*)(ws + 0 * S);
  unsigned short* h1b  = (unsigned short*)(ws + 1 * S);
  unsigned short* h2b  = (unsigned short*)(ws + 2 * S);
  unsigned short* Wqb = (unsigned short*)(ws + 6 * S);
  unsigned short* Wkb = Wqb + (size_t)1024 * 1024;
  unsigned short* Wvb = Wkb + (size_t)1024 * 1024;
  unsigned short* Wob = Wvb + (size_t)1024 * 1024;

  cvt_w<<<4096, 256, 0, stream>>>(Wq, Wk, Wv, Wo, Wqb, Wkb, Wvb, Wob);

  gemm_proj3<<<dim3(64, 8, 3), 256, 0, stream>>>(
      q, k, v, Wqb, Wkb, Wvb, qpb, kpb, vpb, 8192, 1024, 1024);

  attn_fused<<<512, 256, 0, stream>>>(qpb, kpb, vpb, msk, attb);

  add_ln<0><<<8192, 256, 0, stream>>>(qpb, attb, g1, b1, (void*)h1b);
  gemm_bt<1><<<dim3(64, 8), 256, 0, stream>>>(h1b, Wob, h2b, bo, 8192, 1024, 1024);
  add_ln<1><<<8192, 256, 0, stream>>>(h1b, h2b, g2, b2, (void*)out);
}